// Round 5
// baseline (341.280 us; speedup 1.0000x reference)
//
#include <hip/hip_runtime.h>

#define BETA    0.9f
#define T_STEPS 32
#define N_IN    256
#define N_H     64
#define N_C     3
#define BLOCK   128            // 2 waves per block
#define SPB     128            // samples per block (2 per thread)
#define HALF    32             // hidden neurons per wave (j-split)
#define KT      32             // k-tile width
#define NKT     (N_IN / KT)    // 8 tiles
#define XROW    130            // xt row stride in words: 2-way banks only

// Each thread owns samples (b0+lane) and (b0+lane+64).
// wave0 owns j=0..31, wave1 owns j=32..63.
// I1: ascending-k serial fma per j (identical to prior rounds).
// Drives: ascending-j serial fma, wave0 prefix -> dbuf -> wave1 suffix,
// pipelined in chunks of 2 timesteps (wave0 runs one chunk ahead).
__global__ __launch_bounds__(BLOCK, 2) void snn_fused_kernel(
    const float* __restrict__ x,    // (B, 256)
    const float* __restrict__ W1,   // (64, 256)
    const float* __restrict__ W2,   // (3, 64)
    float* __restrict__ out)        // (B, 3)
{
    __shared__ float xt[KT][XROW];         // x tile transposed [k][sample]
    __shared__ float w1r[N_H][KT];         // W1 tile row-major [j][k], b128-aligned
    __shared__ float w2l[N_C][N_H];        // W2 rows
    __shared__ float dbuf[4][SPB][4];      // prefix drives, slot = t & 3

    const int tid  = threadIdx.x;
    const int lane = tid & 63;
    const int wv   = tid >> 6;             // 0 or 1
    const int b0   = blockIdx.x * SPB;
    const int jb   = wv * HALF;

    // stage W2 once (192 floats); fenced by the first kt-loop barrier
    for (int i = tid; i < N_C * N_H; i += BLOCK)
        (&w2l[0][0])[i] = W2[i];

    float I1a[HALF], I1b[HALF];
#pragma unroll
    for (int j = 0; j < HALF; ++j) { I1a[j] = 0.f; I1b[j] = 0.f; }

    // ---------------- Phase 1: I1 = x @ W1^T ----------------
#pragma unroll 1
    for (int kt = 0; kt < NKT; ++kt) {
        __syncthreads();   // previous tile consumed (and w2l staged at kt=0)

        // stage x[b0..b0+128][kt*32..+32] transposed: 1024 float4, 8/thread
#pragma unroll
        for (int i = 0; i < 8; ++i) {
            const int L  = tid + i * BLOCK;   // 0..1023
            const int s  = L >> 3;            // sample 0..127
            const int k4 = L & 7;
            const float4 v = *reinterpret_cast<const float4*>(
                x + (size_t)(b0 + s) * N_IN + kt * KT + k4 * 4);
            xt[k4 * 4 + 0][s] = v.x;          // bank = (8*k4 + c*2 + a)%32: 2-way, free
            xt[k4 * 4 + 1][s] = v.y;
            xt[k4 * 4 + 2][s] = v.z;
            xt[k4 * 4 + 3][s] = v.w;
        }
        // stage W1 tile row-major: 512 float4, 4/thread, contiguous b128 writes
#pragma unroll
        for (int i = 0; i < 4; ++i) {
            const int L  = tid + i * BLOCK;   // 0..511
            const int j  = L >> 3;            // 0..63
            const int k4 = L & 7;
            const float4 v = *reinterpret_cast<const float4*>(
                W1 + (size_t)j * N_IN + kt * KT + k4 * 4);
            *reinterpret_cast<float4*>(&w1r[j][k4 * 4]) = v;  // balanced banks
        }
        __syncthreads();

        // my two samples' x values for this k-tile (per-lane b32, 2-way banks)
        float xva[KT], xvb[KT];
#pragma unroll
        for (int kk = 0; kk < KT; ++kk) {
            xva[kk] = xt[kk][lane];
            xvb[kk] = xt[kk][lane + 64];
        }

        // j-outer, k-inner: each uniform b128 W-read feeds 8 FMAs (2 samples x 4k).
        // Per-I1[j] order: ascending k serial — unchanged arithmetic.
#pragma unroll
        for (int jj = 0; jj < HALF; ++jj) {
            const float4* wrow =
                reinterpret_cast<const float4*>(&w1r[jb + jj][0]);  // wave-uniform
            float aA = I1a[jj], aB = I1b[jj];
#pragma unroll
            for (int g = 0; g < 8; ++g) {
                const float4 w = wrow[g];
                aA = fmaf(xva[4 * g + 0], w.x, aA);
                aA = fmaf(xva[4 * g + 1], w.y, aA);
                aA = fmaf(xva[4 * g + 2], w.z, aA);
                aA = fmaf(xva[4 * g + 3], w.w, aA);
                aB = fmaf(xvb[4 * g + 0], w.x, aB);
                aB = fmaf(xvb[4 * g + 1], w.y, aB);
                aB = fmaf(xvb[4 * g + 2], w.z, aB);
                aB = fmaf(xvb[4 * g + 3], w.w, aB);
            }
            I1a[jj] = aA; I1b[jj] = aB;
        }
    }
    __syncthreads();

    // ---------------- Phase 2: LIF dynamics ----------------
    float v1a[HALF], v1b[HALF];
#pragma unroll
    for (int j = 0; j < HALF; ++j) { v1a[j] = 0.f; v1b[j] = 0.f; }
    // layer-2 state + counts for the two samples (wave1 only uses these)
    float pA0 = 0.f, pA1 = 0.f, pA2 = 0.f, cA0 = 0.f, cA1 = 0.f, cA2 = 0.f;
    float pB0 = 0.f, pB1 = 0.f, pB2 = 0.f, cB0 = 0.f, cB1 = 0.f, cB2 = 0.f;

    const float4* w20 = reinterpret_cast<const float4*>(&w2l[0][jb]);
    const float4* w21 = reinterpret_cast<const float4*>(&w2l[1][jb]);
    const float4* w22 = reinterpret_cast<const float4*>(&w2l[2][jb]);

#define LIF_A(JJ, WX0, WX1, WX2) {                       \
        float v = fmaf(BETA, v1a[JJ], I1a[JJ]);          \
        float s = (v >= 1.0f) ? 1.0f : 0.0f;             \
        v1a[JJ] = v - s;                                 \
        d0a = fmaf(s, WX0, d0a);                         \
        d1a = fmaf(s, WX1, d1a);                         \
        d2a = fmaf(s, WX2, d2a); }
#define LIF_B(JJ, WX0, WX1, WX2) {                       \
        float v = fmaf(BETA, v1b[JJ], I1b[JJ]);          \
        float s = (v >= 1.0f) ? 1.0f : 0.0f;             \
        v1b[JJ] = v - s;                                 \
        d0b = fmaf(s, WX0, d0b);                         \
        d1b = fmaf(s, WX1, d1b);                         \
        d2b = fmaf(s, WX2, d2b); }
#define LIF_BLOCK                                        \
    _Pragma("unroll")                                    \
    for (int g = 0; g < 8; ++g) {                        \
        const float4 wa = w20[g];                        \
        const float4 wb = w21[g];                        \
        const float4 wc = w22[g];                        \
        LIF_A(4 * g + 0, wa.x, wb.x, wc.x)               \
        LIF_A(4 * g + 1, wa.y, wb.y, wc.y)               \
        LIF_A(4 * g + 2, wa.z, wb.z, wc.z)               \
        LIF_A(4 * g + 3, wa.w, wb.w, wc.w)               \
        LIF_B(4 * g + 0, wa.x, wb.x, wc.x)               \
        LIF_B(4 * g + 1, wa.y, wb.y, wc.y)               \
        LIF_B(4 * g + 2, wa.z, wb.z, wc.z)               \
        LIF_B(4 * g + 3, wa.w, wb.w, wc.w)               \
    }

#pragma unroll 1
    for (int c = 0; c < T_STEPS / 2 + 1; ++c) {
#pragma unroll 1
        for (int tt = 0; tt < 2; ++tt) {
            if (wv == 0) {
                if (c < T_STEPS / 2) {
                    const int t = 2 * c + tt;
                    float d0a = 0.f, d1a = 0.f, d2a = 0.f;
                    float d0b = 0.f, d1b = 0.f, d2b = 0.f;
                    LIF_BLOCK
                    *reinterpret_cast<float4*>(&dbuf[t & 3][lane][0]) =
                        make_float4(d0a, d1a, d2a, 0.f);
                    *reinterpret_cast<float4*>(&dbuf[t & 3][lane + 64][0]) =
                        make_float4(d0b, d1b, d2b, 0.f);
                }
            } else {
                if (c >= 1) {
                    const int t = 2 * (c - 1) + tt;
                    const float4 pa =
                        *reinterpret_cast<const float4*>(&dbuf[t & 3][lane][0]);
                    const float4 pb =
                        *reinterpret_cast<const float4*>(&dbuf[t & 3][lane + 64][0]);
                    float d0a = pa.x, d1a = pa.y, d2a = pa.z;
                    float d0b = pb.x, d1b = pb.y, d2b = pb.z;
                    LIF_BLOCK     // continues the same serial j-order (suffix)
                    {   // layer 2, sample A
                        float v, s;
                        v = fmaf(BETA, pA0, d0a); s = (v >= 1.0f) ? 1.0f : 0.0f;
                        pA0 = v - s; cA0 += s;
                        v = fmaf(BETA, pA1, d1a); s = (v >= 1.0f) ? 1.0f : 0.0f;
                        pA1 = v - s; cA1 += s;
                        v = fmaf(BETA, pA2, d2a); s = (v >= 1.0f) ? 1.0f : 0.0f;
                        pA2 = v - s; cA2 += s;
                    }
                    {   // layer 2, sample B
                        float v, s;
                        v = fmaf(BETA, pB0, d0b); s = (v >= 1.0f) ? 1.0f : 0.0f;
                        pB0 = v - s; cB0 += s;
                        v = fmaf(BETA, pB1, d1b); s = (v >= 1.0f) ? 1.0f : 0.0f;
                        pB1 = v - s; cB1 += s;
                        v = fmaf(BETA, pB2, d2b); s = (v >= 1.0f) ? 1.0f : 0.0f;
                        pB2 = v - s; cB2 += s;
                    }
                }
            }
        }
        __syncthreads();   // publishes wave0's chunk; protects slot reuse
    }

    if (wv == 1) {
        const size_t bA = (size_t)(b0 + lane) * N_C;
        const size_t bB = (size_t)(b0 + lane + 64) * N_C;
        out[bA + 0] = cA0; out[bA + 1] = cA1; out[bA + 2] = cA2;
        out[bB + 0] = cB0; out[bB + 1] = cB1; out[bB + 2] = cB2;
    }
}

extern "C" void kernel_launch(void* const* d_in, const int* in_sizes, int n_in,
                              void* d_out, int out_size, void* d_ws, size_t ws_size,
                              hipStream_t stream) {
    const float* x  = (const float*)d_in[0];
    const float* W1 = (const float*)d_in[1];
    const float* W2 = (const float*)d_in[2];
    float* out = (float*)d_out;

    const int B = in_sizes[0] / N_IN;              // 131072
    snn_fused_kernel<<<B / SPB, BLOCK, 0, stream>>>(x, W1, W2, out);
}

// Round 10
// 310.707 us; speedup vs baseline: 1.0984x; 1.0984x over previous
//
#include <hip/hip_runtime.h>

#define BETA    0.9f
#define T_STEPS 32
#define N_IN    256
#define N_H     64
#define N_C     3
#define BLOCK   128            // 2 waves per block
#define SAMPLES 64             // samples per block (lane = sample)
#define HALF    32             // hidden neurons per wave (j-split)
#define KT      32             // k-tile width
#define NKT     (N_IN / KT)    // 8 tiles
#define XROW    65             // xt row stride: store bank = 4k4+c+s -> 2-way (free)

typedef float v2f __attribute__((ext_vector_type(2)));

static __device__ __forceinline__ v2f mk2(float a, float b) {
    v2f r; r.x = a; r.y = b; return r;
}
static __device__ __forceinline__ v2f fma2(v2f a, v2f b, v2f c) {
    return __builtin_elementwise_fma(a, b, c);   // -> v_pk_fma_f32 (component-wise IEEE fma)
}

// Round-3 structure: 64 samples/block, wave0 owns j=0..31, wave1 owns j=32..63.
// I1: ascending-k serial fma per neuron (bit-identical to prior passing rounds).
// Drives: ascending-j serial fma per channel; wave0 prefix -> dbuf -> wave1 suffix.
// New: conflict-free LDS staging (xt stride 65; w1t XOR-swizzled) + v_pk_fma packing.
__global__ __launch_bounds__(BLOCK, 4) void snn_fused_kernel(
    const float* __restrict__ x,    // (B, 256)
    const float* __restrict__ W1,   // (64, 256)
    const float* __restrict__ W2,   // (3, 64)
    float* __restrict__ out)        // (B, 3)
{
    __shared__ float xt[KT][XROW];      // x tile transposed [k][sample]
    __shared__ float w1t[KT][N_H];      // W1 tile transposed [k][j], j XOR-swizzled
    __shared__ float w2i[2 * N_H];      // interleaved (W2[0][j], W2[1][j])
    __shared__ float w2r2[N_H];         // W2[2][j]
    __shared__ float dbuf[2][SAMPLES][3];  // stride-3: 2-way banks (round-3 proven)

    const int tid  = threadIdx.x;
    const int lane = tid & 63;          // sample within block
    const int wv   = tid >> 6;          // 0 or 1
    const int b0   = blockIdx.x * SAMPLES;
    const int b    = b0 + lane;
    const int jb   = wv * HALF;         // my j-range base
    const int pb   = jb >> 1;           // my j-pair base

    // stage W2 once (fenced by first kt barrier)
    if (tid < N_H) {
        w2i[2 * tid + 0] = W2[0 * N_H + tid];
        w2i[2 * tid + 1] = W2[1 * N_H + tid];
        w2r2[tid]        = W2[2 * N_H + tid];
    }

    v2f I1p[HALF / 2];                  // I1p[p] = (I1[jb+2p], I1[jb+2p+1])
#pragma unroll
    for (int p = 0; p < HALF / 2; ++p) I1p[p] = mk2(0.f, 0.f);

    // ---------------- Phase 1: I1 = x @ W1^T ----------------
#pragma unroll 1
    for (int kt = 0; kt < NKT; ++kt) {
        __syncthreads();   // previous tile consumed (and w2 staged at kt=0)

        // stage x[b0..+64][kt*32..+32] transposed: 512 float4, 4/thread
#pragma unroll
        for (int i = 0; i < 4; ++i) {
            const int L  = tid + i * BLOCK;   // 0..511
            const int s  = L >> 3;            // sample 0..63
            const int k4 = L & 7;
            const float4 v = *reinterpret_cast<const float4*>(
                x + (size_t)(b0 + s) * N_IN + kt * KT + k4 * 4);
            xt[k4 * 4 + 0][s] = v.x;          // bank=(4k4+c+s)%32: exact 2-way, free
            xt[k4 * 4 + 1][s] = v.y;
            xt[k4 * 4 + 2][s] = v.z;
            xt[k4 * 4 + 3][s] = v.w;
        }
        // stage W1 tile transposed + XOR-swizzled: w1t[k][ j ^ ((k>>2)<<3) ]
#pragma unroll
        for (int i = 0; i < 4; ++i) {
            const int L  = tid + i * BLOCK;   // 0..511
            const int j  = L >> 3;            // 0..63
            const int k4 = L & 7;
            const float4 v = *reinterpret_cast<const float4*>(
                W1 + (size_t)j * N_IN + kt * KT + k4 * 4);
            const int js = j ^ (k4 << 3);     // swz = (k>>2)<<3, k = 4k4+c
            w1t[k4 * 4 + 0][js] = v.x;        // bank: 2-way only
            w1t[k4 * 4 + 1][js] = v.y;
            w1t[k4 * 4 + 2][js] = v.z;
            w1t[k4 * 4 + 3][js] = v.w;
        }
        __syncthreads();

        // kk-outer, j-quad inner: uniform swizzled b128 reads, 16 pk_fma per kk.
        // Per-neuron order: ascending k serial — unchanged arithmetic.
#pragma unroll
        for (int kk = 0; kk < KT; ++kk) {
            const float xk = xt[kk][lane];           // per-lane b32, 2-way banks
            const v2f xkp = mk2(xk, xk);
            const int swz = (kk >> 2) << 3;
#pragma unroll
            for (int q = 0; q < 8; ++q) {            // j-quad: jb+4q .. +3
                const float4 w = *reinterpret_cast<const float4*>(
                    &w1t[kk][(jb + 4 * q) ^ swz]);   // uniform -> broadcast, 16B-aligned
                I1p[2 * q + 0] = fma2(xkp, mk2(w.x, w.y), I1p[2 * q + 0]);
                I1p[2 * q + 1] = fma2(xkp, mk2(w.z, w.w), I1p[2 * q + 1]);
            }
        }
    }
    __syncthreads();

    // ---------------- Phase 2: pipelined LIF ----------------
    v2f v1p[HALF / 2];
#pragma unroll
    for (int p = 0; p < HALF / 2; ++p) v1p[p] = mk2(0.f, 0.f);

    const v2f beta2 = mk2(BETA, BETA);
    // layer-2 state (wave1): channels 0,1 packed; channel 2 scalar
    v2f p01 = mk2(0.f, 0.f), c01 = mk2(0.f, 0.f);
    float p2 = 0.f, c2 = 0.f;

#pragma unroll 1
    for (int it = 0; it < T_STEPS + 1; ++it) {
        if (wv == 0) {
            if (it < T_STEPS) {
                v2f d01 = mk2(0.f, 0.f);             // (d0, d1) channel pair
                float d2 = 0.f;
#pragma unroll
                for (int p = 0; p < HALF / 2; ++p) {
                    const float4 w01 = *reinterpret_cast<const float4*>(
                        &w2i[4 * (pb + p)]);          // (w0[j],w1[j],w0[j+1],w1[j+1])
                    const v2f w2p = *reinterpret_cast<const v2f*>(
                        &w2r2[2 * (pb + p)]);
                    v2f v = fma2(beta2, v1p[p], I1p[p]);
                    const float s0 = (v.x >= 1.0f) ? 1.0f : 0.0f;
                    const float s1 = (v.y >= 1.0f) ? 1.0f : 0.0f;
                    v1p[p] = v - mk2(s0, s1);
                    d01 = fma2(mk2(s0, s0), mk2(w01.x, w01.y), d01);  // j even
                    d2  = fmaf(s0, w2p.x, d2);
                    d01 = fma2(mk2(s1, s1), mk2(w01.z, w01.w), d01);  // j odd
                    d2  = fmaf(s1, w2p.y, d2);
                }
                dbuf[it & 1][lane][0] = d01.x;
                dbuf[it & 1][lane][1] = d01.y;
                dbuf[it & 1][lane][2] = d2;
            }
        } else {
            if (it >= 1) {
                v2f d01 = mk2(dbuf[(it - 1) & 1][lane][0],
                              dbuf[(it - 1) & 1][lane][1]);
                float d2 = dbuf[(it - 1) & 1][lane][2];
#pragma unroll
                for (int p = 0; p < HALF / 2; ++p) {
                    const float4 w01 = *reinterpret_cast<const float4*>(
                        &w2i[4 * (pb + p)]);
                    const v2f w2p = *reinterpret_cast<const v2f*>(
                        &w2r2[2 * (pb + p)]);
                    v2f v = fma2(beta2, v1p[p], I1p[p]);
                    const float s0 = (v.x >= 1.0f) ? 1.0f : 0.0f;
                    const float s1 = (v.y >= 1.0f) ? 1.0f : 0.0f;
                    v1p[p] = v - mk2(s0, s1);
                    d01 = fma2(mk2(s0, s0), mk2(w01.x, w01.y), d01);  // serial j cont.
                    d2  = fmaf(s0, w2p.x, d2);
                    d01 = fma2(mk2(s1, s1), mk2(w01.z, w01.w), d01);
                    d2  = fmaf(s1, w2p.y, d2);
                }
                // layer 2: channels 0,1 packed (component-wise), channel 2 scalar
                {
                    v2f v = fma2(beta2, p01, d01);
                    const float s0 = (v.x >= 1.0f) ? 1.0f : 0.0f;
                    const float s1 = (v.y >= 1.0f) ? 1.0f : 0.0f;
                    p01 = v - mk2(s0, s1);
                    c01 = c01 + mk2(s0, s1);
                }
                {
                    float v = fmaf(BETA, p2, d2);
                    float s = (v >= 1.0f) ? 1.0f : 0.0f;
                    p2 = v - s;  c2 += s;
                }
            }
        }
        __syncthreads();   // publishes wave0's step t to wave1; protects slot reuse
    }

    if (wv == 1) {
        out[(size_t)b * N_C + 0] = c01.x;
        out[(size_t)b * N_C + 1] = c01.y;
        out[(size_t)b * N_C + 2] = c2;
    }
}

extern "C" void kernel_launch(void* const* d_in, const int* in_sizes, int n_in,
                              void* d_out, int out_size, void* d_ws, size_t ws_size,
                              hipStream_t stream) {
    const float* x  = (const float*)d_in[0];
    const float* W1 = (const float*)d_in[1];
    const float* W2 = (const float*)d_in[2];
    float* out = (float*)d_out;

    const int B = in_sizes[0] / N_IN;              // 131072
    snn_fused_kernel<<<B / SAMPLES, BLOCK, 0, stream>>>(x, W1, W2, out);
}